// Round 1
// baseline (31.758 us; speedup 1.0000x reference)
//
#include <hip/hip_runtime.h>
#include <hip/hip_bf16.h>

using floatx4 = __attribute__((ext_vector_type(4))) float;
using shortx8 = __attribute__((ext_vector_type(8))) short;

constexpr int M = 32, N = 4096, K = 4096;
constexpr int SPLITK = 16;
constexpr int KC = K / SPLITK;   // 256

// init: out = bias (poison-safe re-init every call), x -> bf16 staged in ws
__global__ __launch_bounds__(256) void init_kernel(
    const float* __restrict__ x, const float* __restrict__ bias,
    float* __restrict__ out, short* __restrict__ xbf)
{
    int i = blockIdx.x * blockDim.x + threadIdx.x;
    if (i < M * N) out[i] = bias[i & (N - 1)];
    if (i < M * K) {
        __hip_bfloat16 h = __float2bfloat16(x[i]);
        xbf[i] = *reinterpret_cast<short*>(&h);
    }
}

// Each wave: 16 W-rows x full batch(32), K-chunk of KC. Dequant W in-register,
// 2x mfma_f32_16x16x32_bf16 per k-step sharing the W fragment. Split-K via atomics.
template<bool XBF16>
__global__ __launch_bounds__(256) void gemm_kernel(
    const float* __restrict__ W, const float* __restrict__ scales,
    const short* __restrict__ xbf, const float* __restrict__ xf32,
    const float* __restrict__ tscale, float* __restrict__ out)
{
    const int lane = threadIdx.x & 63;
    const int wave = threadIdx.x >> 6;
    const int o0 = blockIdx.x * 64 + wave * 16;
    const int k0 = blockIdx.y * KC;

    const int row = lane & 15;   // o-offset for B/W frag; b-offset for A/x frag
    const int kg  = lane >> 4;   // k subgroup (8 elems each)

    const float* wp = W + (size_t)(o0 + row) * K + k0 + kg * 8;
    // block index = o*(K/16) + k/16 ; lane's 8 elems sit in ONE block
    const float* sp = scales + (size_t)(o0 + row) * (K / 16) + (k0 >> 4) + (kg >> 1);
    const short* xp0 = xbf + (size_t)row * K + k0 + kg * 8;
    const short* xp1 = xbf + (size_t)(row + 16) * K + k0 + kg * 8;
    const float* xf0 = xf32 + (size_t)row * K + k0 + kg * 8;
    const float* xf1 = xf32 + (size_t)(row + 16) * K + k0 + kg * 8;

    const float rt = 1.0f / tscale[0];

    floatx4 acc0 = {0.f, 0.f, 0.f, 0.f};
    floatx4 acc1 = {0.f, 0.f, 0.f, 0.f};

    #pragma unroll
    for (int kk = 0; kk < KC; kk += 32) {
        floatx4 w0 = *reinterpret_cast<const floatx4*>(wp);
        floatx4 w1 = *reinterpret_cast<const floatx4*>(wp + 4);
        float s = *sp;
        shortx8 xa, xb;
        if constexpr (XBF16) {
            xa = *reinterpret_cast<const shortx8*>(xp0);
            xb = *reinterpret_cast<const shortx8*>(xp1);
        } else {
            floatx4 a0 = *reinterpret_cast<const floatx4*>(xf0);
            floatx4 a1 = *reinterpret_cast<const floatx4*>(xf0 + 4);
            floatx4 b0 = *reinterpret_cast<const floatx4*>(xf1);
            floatx4 b1 = *reinterpret_cast<const floatx4*>(xf1 + 4);
            float av[8] = {a0[0],a0[1],a0[2],a0[3],a1[0],a1[1],a1[2],a1[3]};
            float bv[8] = {b0[0],b0[1],b0[2],b0[3],b1[0],b1[1],b1[2],b1[3]};
            #pragma unroll
            for (int i = 0; i < 8; ++i) {
                __hip_bfloat16 ha = __float2bfloat16(av[i]);
                __hip_bfloat16 hb = __float2bfloat16(bv[i]);
                xa[i] = *reinterpret_cast<short*>(&ha);
                xb[i] = *reinterpret_cast<short*>(&hb);
            }
        }
        const float rs = rt / s;   // w/(s*t) == w * (rt/s)
        shortx8 wf;
        float wv[8] = {w0[0],w0[1],w0[2],w0[3],w1[0],w1[1],w1[2],w1[3]};
        #pragma unroll
        for (int i = 0; i < 8; ++i) {
            __hip_bfloat16 h = __float2bfloat16(wv[i] * rs);
            wf[i] = *reinterpret_cast<short*>(&h);
        }
        acc0 = __builtin_amdgcn_mfma_f32_16x16x32_bf16(xa, wf, acc0, 0, 0, 0);
        acc1 = __builtin_amdgcn_mfma_f32_16x16x32_bf16(xb, wf, acc1, 0, 0, 0);
        wp += 32; sp += 2; xp0 += 32; xp1 += 32; xf0 += 32; xf1 += 32;
    }

    // D[row=(lane>>4)*4+r][col=lane&15]: row = batch, col = o  -> coalesced atomics
    float* op0 = out + (size_t)(kg * 4) * N + o0 + row;
    float* op1 = out + (size_t)(16 + kg * 4) * N + o0 + row;
    #pragma unroll
    for (int r = 0; r < 4; ++r) {
        atomicAdd(op0 + (size_t)r * N, acc0[r]);
        atomicAdd(op1 + (size_t)r * N, acc1[r]);
    }
}

extern "C" void kernel_launch(void* const* d_in, const int* in_sizes, int n_in,
                              void* d_out, int out_size, void* d_ws, size_t ws_size,
                              hipStream_t stream)
{
    const float* x      = (const float*)d_in[0];
    const float* W      = (const float*)d_in[1];
    const float* tscale = (const float*)d_in[2];
    const float* scales = (const float*)d_in[3];
    const float* bias   = (const float*)d_in[4];
    float* out = (float*)d_out;
    short* xbf = (short*)d_ws;                    // needs M*K*2 = 256 KiB

    const bool use_ws = (ws_size >= (size_t)M * K * sizeof(short));

    init_kernel<<<(M * N + 255) / 256, 256, 0, stream>>>(x, bias, out, xbf);

    dim3 grid(N / 64, SPLITK);
    if (use_ws)
        gemm_kernel<true><<<grid, 256, 0, stream>>>(W, scales, xbf, x, tscale, out);
    else
        gemm_kernel<false><<<grid, 256, 0, stream>>>(W, scales, xbf, x, tscale, out);
}